// Round 1
// baseline (15809.981 us; speedup 1.0000x reference)
//
#include <hip/hip_runtime.h>
#include <hip/hip_bf16.h>
#include <math.h>

#define B   128
#define NN  36
#define FF  2048
#define AA  1024
#define EE  1024
#define DD  1024
#define VV  10000
#define LL  20
#define TT  19

// ---------------- sort (stable descending by length) ----------------
__global__ __launch_bounds__(B) void sort_kernel(const int* __restrict__ cap_len,
                                                 int* __restrict__ sort_ind,
                                                 int* __restrict__ dec_len) {
    __shared__ int lsh[B];
    int i = threadIdx.x;
    lsh[i] = cap_len[i];            // caption_lengths is (B,1)
    __syncthreads();
    int li = lsh[i];
    int rank = 0;
    for (int j = 0; j < B; ++j) {
        int lj = lsh[j];
        rank += (lj > li) || (lj == li && j < i);   // stable descending
    }
    sort_ind[rank] = i;
    dec_len[rank]  = li - 1;
}

// ---------------- feats_mean (permuted) ----------------
__global__ void feats_mean_kernel(const float* __restrict__ img,
                                  const int* __restrict__ sort_ind,
                                  float* __restrict__ fm) {
    int idx = blockIdx.x * blockDim.x + threadIdx.x;   // B*FF threads
    int b = idx >> 11;          // FF = 2048
    int f = idx & 2047;
    const float* src = img + (size_t)sort_ind[b] * (NN * FF) + f;
    float s = 0.f;
#pragma unroll
    for (int n = 0; n < NN; ++n) s += src[n * FF];
    fm[idx] = s * (1.0f / NN);
}

// ---------------- x1 = [h2 | feats_mean | emb_t] ----------------
__global__ void build_x1_kernel(const float* __restrict__ h2,
                                const float* __restrict__ fm,
                                const float* __restrict__ emb,
                                const int* __restrict__ caps,
                                const int* __restrict__ sort_ind,
                                int t,
                                float* __restrict__ x1) {
    int idx = blockIdx.x * blockDim.x + threadIdx.x;   // B*4096
    int b = idx >> 12;
    int j = idx & 4095;
    float v;
    if (j < DD) {
        v = h2[b * DD + j];
    } else if (j < DD + FF) {
        v = fm[b * FF + (j - DD)];
    } else {
        int cap = caps[sort_ind[b] * LL + t];
        v = emb[(size_t)cap * EE + (j - DD - FF)];
    }
    x1[idx] = v;
}

// ---------------- x2 = [awe | h1] ----------------
__global__ void build_x2_kernel(const float* __restrict__ awe,
                                const float* __restrict__ h1,
                                float* __restrict__ x2) {
    int idx = blockIdx.x * blockDim.x + threadIdx.x;   // B*3072
    int b = idx / 3072;
    int j = idx % 3072;
    x2[idx] = (j < FF) ? awe[b * FF + j] : h1[b * DD + (j - FF)];
}

// ---------------- LSTM pointwise (in-place, masked) ----------------
__global__ void lstm_cell_kernel(const float* __restrict__ g,
                                 float* __restrict__ h,
                                 float* __restrict__ c,
                                 const int* __restrict__ dec_len,
                                 int t) {
    int idx = blockIdx.x * blockDim.x + threadIdx.x;   // B*DD
    int b = idx >> 10;
    int d = idx & 1023;
    const float* gb = g + (size_t)b * 4 * DD;
    float gi = gb[d];
    float gf = gb[DD + d];
    float gg = gb[2 * DD + d];
    float go = gb[3 * DD + d];
    float si = 1.f / (1.f + expf(-gi));
    float sf = 1.f / (1.f + expf(-gf));
    float so = 1.f / (1.f + expf(-go));
    float c2 = sf * c[idx] + si * tanhf(gg);
    float h2 = so * tanhf(c2);
    if (t < dec_len[b]) {      // inactive rows keep old h,c (reference blend)
        h[idx] = h2;
        c[idx] = c2;
    }
}

// ---------------- fused attention: scores -> softmax -> weighted sum ----------------
__global__ __launch_bounds__(256) void attention_kernel(
        const float* __restrict__ att1,   // (B,NN,AA)
        const float* __restrict__ att2,   // (B,AA)
        const float* __restrict__ Wa,     // (AA)
        const float* __restrict__ ba,     // (1)
        const float* __restrict__ img,    // (B,NN,FF) original order
        const int* __restrict__ sort_ind,
        float* __restrict__ awe) {        // (B,FF)
    int b = blockIdx.x;
    __shared__ float alpha[NN];
    int tid  = threadIdx.x;
    int wave = tid >> 6;
    int lane = tid & 63;

    // scores e[n] = relu(att1[b,n,:] + att2[b,:]) . Wa + ba
    for (int n = wave; n < NN; n += 4) {
        const float* a1 = att1 + ((size_t)b * NN + n) * AA;
        const float* a2 = att2 + (size_t)b * AA;
        float p = 0.f;
        for (int a = lane; a < AA; a += 64) {
            float v = a1[a] + a2[a];
            v = v > 0.f ? v : 0.f;
            p += v * Wa[a];
        }
        for (int off = 32; off; off >>= 1) p += __shfl_down(p, off);
        if (lane == 0) alpha[n] = p + ba[0];
    }
    __syncthreads();

    // softmax over NN=36 (wave 0)
    if (wave == 0) {
        float e = (lane < NN) ? alpha[lane] : -INFINITY;
        float m = e;
        for (int off = 32; off; off >>= 1) m = fmaxf(m, __shfl_down(m, off));
        m = __shfl(m, 0);
        float ex = (lane < NN) ? expf(e - m) : 0.f;
        float s = ex;
        for (int off = 32; off; off >>= 1) s += __shfl_down(s, off);
        s = __shfl(s, 0);
        if (lane < NN) alpha[lane] = ex / s;
    }
    __syncthreads();

    // awe[b,f] = sum_n alpha[n] * feats[b,n,f]
    const float* src = img + (size_t)sort_ind[b] * (NN * FF);
    for (int f = tid; f < FF; f += 256) {
        float s = 0.f;
#pragma unroll
        for (int n = 0; n < NN; ++n) s += alpha[n] * src[n * FF + f];
        awe[(size_t)b * FF + f] = s;
    }
}

// ---------------- generic tiled SGEMM: C = A(M,K) * W(N,K)^T [+C] [+bias] ----------------
// Optional row permutation on A (src_row = perm[row/rpb]*rpb + row%rpb).
// Optional row masking for preds (row inactive if tstep >= dec_len[row] -> write 0).
#define GBM 64
#define GBN 64
#define GBK 16

__global__ __launch_bounds__(256) void gemm_nt(
        const float* __restrict__ A, int lda,
        const float* __restrict__ W, int ldw,
        const float* __restrict__ bias,
        float* __restrict__ C, int ldc,
        int M, int N, int K,
        int accumulate,
        const int* __restrict__ rowperm, int rpb,
        const int* __restrict__ dec_len, int tstep) {
    __shared__ float As[GBK][GBM + 4];
    __shared__ float Ws[GBK][GBN + 4];
    int bm = blockIdx.x * GBM;
    int bn = blockIdx.y * GBN;
    int tid = threadIdx.x;
    int tx = tid & 15;     // N direction
    int ty = tid >> 4;     // M direction
    float acc[4][4] = {{0.f}};

    int lr = tid >> 2;           // 0..63 (tile row)
    int lk = (tid & 3) << 2;     // 0,4,8,12 (k offset, float4)

    for (int k0 = 0; k0 < K; k0 += GBK) {
        // stage A tile (GBM x GBK) as As[k][m]
        {
            int ga = bm + lr;
            float4 av = make_float4(0.f, 0.f, 0.f, 0.f);
            if (ga < M) {
                int sr = rowperm ? (rowperm[ga / rpb] * rpb + (ga % rpb)) : ga;
                av = *(const float4*)(A + (size_t)sr * lda + k0 + lk);
            }
            As[lk + 0][lr] = av.x; As[lk + 1][lr] = av.y;
            As[lk + 2][lr] = av.z; As[lk + 3][lr] = av.w;
        }
        // stage W tile (GBN x GBK) as Ws[k][n]
        {
            int gw = bn + lr;
            float4 wv = make_float4(0.f, 0.f, 0.f, 0.f);
            if (gw < N) wv = *(const float4*)(W + (size_t)gw * ldw + k0 + lk);
            Ws[lk + 0][lr] = wv.x; Ws[lk + 1][lr] = wv.y;
            Ws[lk + 2][lr] = wv.z; Ws[lk + 3][lr] = wv.w;
        }
        __syncthreads();
#pragma unroll
        for (int kk = 0; kk < GBK; ++kk) {
            float4 a4 = *(const float4*)&As[kk][ty << 2];
            float4 b4 = *(const float4*)&Ws[kk][tx << 2];
            float a[4] = {a4.x, a4.y, a4.z, a4.w};
            float bb[4] = {b4.x, b4.y, b4.z, b4.w};
#pragma unroll
            for (int i = 0; i < 4; ++i)
#pragma unroll
                for (int j = 0; j < 4; ++j)
                    acc[i][j] = fmaf(a[i], bb[j], acc[i][j]);
        }
        __syncthreads();
    }

#pragma unroll
    for (int i = 0; i < 4; ++i) {
        int m = bm + (ty << 2) + i;
        if (m >= M) continue;
        int act = dec_len ? (tstep < dec_len[m] ? 1 : 0) : 1;
#pragma unroll
        for (int j = 0; j < 4; ++j) {
            int n = bn + (tx << 2) + j;
            if (n >= N) continue;
            float v = acc[i][j];
            if (accumulate) v += C[(size_t)m * ldc + n];
            if (bias) v += bias[n];
            C[(size_t)m * ldc + n] = act ? v : 0.0f;
        }
    }
}

// ---------------- host launcher ----------------
extern "C" void kernel_launch(void* const* d_in, const int* in_sizes, int n_in,
                              void* d_out, int out_size, void* d_ws, size_t ws_size,
                              hipStream_t stream) {
    const float* img     = (const float*)d_in[0];
    const int*   caps    = (const int*)d_in[1];
    const int*   cap_len = (const int*)d_in[2];
    const float* emb     = (const float*)d_in[3];
    const float* W1_ih   = (const float*)d_in[4];
    const float* W1_hh   = (const float*)d_in[5];
    const float* b1_ih   = (const float*)d_in[6];
    const float* b1_hh   = (const float*)d_in[7];
    const float* W2_ih   = (const float*)d_in[8];
    const float* W2_hh   = (const float*)d_in[9];
    const float* b2_ih   = (const float*)d_in[10];
    const float* b2_hh   = (const float*)d_in[11];
    const float* Wf      = (const float*)d_in[12];
    const float* bf      = (const float*)d_in[13];
    const float* Wd      = (const float*)d_in[14];
    const float* bd      = (const float*)d_in[15];
    const float* Wa      = (const float*)d_in[16];
    const float* ba      = (const float*)d_in[17];
    const float* Wfc     = (const float*)d_in[18];
    const float* bfc     = (const float*)d_in[19];
    float* out = (float*)d_out;

    // workspace layout
    char* ws = (char*)d_ws;
    size_t off = 0;
    auto alloc = [&](size_t bytes) -> void* {
        void* p = ws + off;
        off += (bytes + 255) & ~(size_t)255;
        return p;
    };
    int*   sort_ind = (int*)alloc(B * sizeof(int));
    int*   dec_len  = (int*)alloc(B * sizeof(int));
    float* fm       = (float*)alloc((size_t)B * FF * 4);
    float* att1     = (float*)alloc((size_t)B * NN * AA * 4);
    float* hc       = (float*)alloc((size_t)4 * B * DD * 4);   // h1,c1,h2,c2
    float* h1 = hc;
    float* c1 = hc + (size_t)B * DD;
    float* h2 = hc + (size_t)2 * B * DD;
    float* c2 = hc + (size_t)3 * B * DD;
    float* x1   = (float*)alloc((size_t)B * 4096 * 4);
    float* g    = (float*)alloc((size_t)B * 4096 * 4);
    float* att2 = (float*)alloc((size_t)B * AA * 4);
    float* awe  = (float*)alloc((size_t)B * FF * 4);
    float* x2   = (float*)alloc((size_t)B * 3072 * 4);
    (void)ws_size; (void)in_sizes; (void)n_in; (void)out_size;

    // init
    sort_kernel<<<1, B, 0, stream>>>(cap_len, sort_ind, dec_len);
    hipMemsetAsync(hc, 0, (size_t)4 * B * DD * 4, stream);
    feats_mean_kernel<<<(B * FF) / 256, 256, 0, stream>>>(img, sort_ind, fm);

    // att1 = feats_sorted @ Wf^T + bf   (M=B*NN, N=AA, K=FF)
    gemm_nt<<<dim3((B * NN) / GBM, AA / GBN), 256, 0, stream>>>(
        img, FF, Wf, FF, bf, att1, AA, B * NN, AA, FF, 0, sort_ind, NN, nullptr, 0);

    for (int t = 0; t < TT; ++t) {
        build_x1_kernel<<<(B * 4096) / 256, 256, 0, stream>>>(h2, fm, emb, caps, sort_ind, t, x1);

        // g = x1 @ W1_ih^T + b1_ih ; g += h1 @ W1_hh^T + b1_hh
        gemm_nt<<<dim3(B / GBM, 4096 / GBN), 256, 0, stream>>>(
            x1, 4096, W1_ih, 4096, b1_ih, g, 4096, B, 4096, 4096, 0, nullptr, 1, nullptr, 0);
        gemm_nt<<<dim3(B / GBM, 4096 / GBN), 256, 0, stream>>>(
            h1, DD, W1_hh, DD, b1_hh, g, 4096, B, 4096, DD, 1, nullptr, 1, nullptr, 0);
        lstm_cell_kernel<<<(B * DD) / 256, 256, 0, stream>>>(g, h1, c1, dec_len, t);

        // att2 = h1 @ Wd^T + bd
        gemm_nt<<<dim3(B / GBM, AA / GBN), 256, 0, stream>>>(
            h1, DD, Wd, DD, bd, att2, AA, B, AA, DD, 0, nullptr, 1, nullptr, 0);

        attention_kernel<<<B, 256, 0, stream>>>(att1, att2, Wa, ba, img, sort_ind, awe);

        build_x2_kernel<<<(B * 3072) / 256, 256, 0, stream>>>(awe, h1, x2);

        // g = x2 @ W2_ih^T + b2_ih ; g += h2 @ W2_hh^T + b2_hh
        gemm_nt<<<dim3(B / GBM, 4096 / GBN), 256, 0, stream>>>(
            x2, 3072, W2_ih, 3072, b2_ih, g, 4096, B, 4096, 3072, 0, nullptr, 1, nullptr, 0);
        gemm_nt<<<dim3(B / GBM, 4096 / GBN), 256, 0, stream>>>(
            h2, DD, W2_hh, DD, b2_hh, g, 4096, B, 4096, DD, 1, nullptr, 1, nullptr, 0);
        lstm_cell_kernel<<<(B * DD) / 256, 256, 0, stream>>>(g, h2, c2, dec_len, t);

        // preds[:, t, :] = active * (h2 @ Wfc^T + bfc)
        gemm_nt<<<dim3(B / GBM, (VV + GBN - 1) / GBN), 256, 0, stream>>>(
            h2, DD, Wfc, DD, bfc, out + (size_t)t * VV, TT * VV, B, VV, DD, 0,
            nullptr, 1, dec_len, t);
    }
}

// Round 2
// 3086.883 us; speedup vs baseline: 5.1217x; 5.1217x over previous
//
#include <hip/hip_runtime.h>
#include <hip/hip_bf16.h>
#include <math.h>

#define B   128
#define NN  36
#define FF  2048
#define AA  1024
#define EE  1024
#define DD  1024
#define VV  10000
#define LL  20
#define TT  19

typedef __attribute__((ext_vector_type(8))) short short8;
typedef __attribute__((ext_vector_type(4))) float floatx4;

// ---------------- sort (stable descending by length) ----------------
__global__ __launch_bounds__(B) void sort_kernel(const int* __restrict__ cap_len,
                                                 int* __restrict__ sort_ind,
                                                 int* __restrict__ dec_len) {
    __shared__ int lsh[B];
    int i = threadIdx.x;
    lsh[i] = cap_len[i];
    __syncthreads();
    int li = lsh[i];
    int rank = 0;
    for (int j = 0; j < B; ++j) {
        int lj = lsh[j];
        rank += (lj > li) || (lj == li && j < i);   // stable descending
    }
    sort_ind[rank] = i;
    dec_len[rank]  = li - 1;
}

// ---------------- fp32 -> bf16 convert ----------------
__global__ void convert_kernel(const float* __restrict__ src,
                               __hip_bfloat16* __restrict__ dst, int n) {
    int i = blockIdx.x * 256 + threadIdx.x;
    if (i < n) dst[i] = __float2bfloat16(src[i]);
}

// ---------------- pack [W1_ih | W1_hh] -> bf16 (4096 x 5120) ----------------
__global__ void pack_w1_kernel(const float* __restrict__ Wih,
                               const float* __restrict__ Whh,
                               __hip_bfloat16* __restrict__ dst) {
    int i = blockIdx.x * 256 + threadIdx.x;     // 4096*5120 threads
    int n = i / 5120, k = i % 5120;
    float v = (k < 4096) ? Wih[(size_t)n * 4096 + k] : Whh[(size_t)n * 1024 + (k - 4096)];
    dst[i] = __float2bfloat16(v);
}

// ---------------- pack [W2_ih | W2_hh] -> bf16 (4096 x 4096) ----------------
__global__ void pack_w2_kernel(const float* __restrict__ Wih,
                               const float* __restrict__ Whh,
                               __hip_bfloat16* __restrict__ dst) {
    int i = blockIdx.x * 256 + threadIdx.x;     // 4096*4096 threads
    int n = i >> 12, k = i & 4095;
    float v = (k < 3072) ? Wih[(size_t)n * 3072 + k] : Whh[(size_t)n * 1024 + (k - 3072)];
    dst[i] = __float2bfloat16(v);
}

// ---------------- sorted feats -> bf16 ----------------
__global__ void feats_bf_kernel(const float* __restrict__ img,
                                const int* __restrict__ sort_ind,
                                __hip_bfloat16* __restrict__ dst) {
    int i = blockIdx.x * 256 + threadIdx.x;     // B*NN*FF threads
    int b = i / (NN * FF);
    int r = i % (NN * FF);
    dst[i] = __float2bfloat16(img[(size_t)sort_ind[b] * (NN * FF) + r]);
}

// ---------------- feats_mean (fp32 accumulate) -> x1full slot [1024..3072) ----------------
__global__ void fm_kernel(const float* __restrict__ img,
                          const int* __restrict__ sort_ind,
                          __hip_bfloat16* __restrict__ x1full) {
    int i = blockIdx.x * 256 + threadIdx.x;     // B*FF threads
    int b = i >> 11;
    int f = i & 2047;
    const float* src = img + (size_t)sort_ind[b] * (NN * FF) + f;
    float s = 0.f;
#pragma unroll
    for (int n = 0; n < NN; ++n) s += src[n * FF];
    x1full[(size_t)b * 5120 + 1024 + f] = __float2bfloat16(s * (1.0f / NN));
}

// ---------------- emb gather -> x1full slot [3072..4096) ----------------
__global__ void emb_gather_kernel(const float* __restrict__ emb,
                                  const int* __restrict__ caps,
                                  const int* __restrict__ sort_ind,
                                  int t,
                                  __hip_bfloat16* __restrict__ x1full) {
    int i = blockIdx.x * 256 + threadIdx.x;     // B*EE threads
    int b = i >> 10;
    int e = i & 1023;
    int cap = caps[sort_ind[b] * LL + t];
    x1full[(size_t)b * 5120 + 3072 + e] = __float2bfloat16(emb[(size_t)cap * EE + e]);
}

// ---------------- bf16 MFMA GEMM: C = A(M,K-chunk) @ W(N,K-chunk)^T ----------------
// Grid: (N/BN, M/BM, splitk). EPI=0: write fp32 partial at C + z*pstride.
// EPI=1: preds epilogue (bias + activity mask + N guard), z grid must be 1.
#define BM 128
#define BN 64
#define BK 64
#define LDS_K 72   // +8 bf16 pad: rows stay 16B aligned, frag reads 2-way max (free)

template<int EPI>
__global__ __launch_bounds__(256) void gemm_bf16(
        const __hip_bfloat16* __restrict__ A, int lda,
        const __hip_bfloat16* __restrict__ W, int ldw,
        float* __restrict__ C, int ldc, size_t pstride,
        int N, int Kc,
        const float* __restrict__ bias,
        const int* __restrict__ dec_len, int tstep) {
    __shared__ __align__(16) short As[BM][LDS_K];
    __shared__ __align__(16) short Wsm[BN][LDS_K];
    const int tid  = threadIdx.x;
    const int bn   = blockIdx.x * BN;
    const int bm   = blockIdx.y * BM;
    const int k0   = blockIdx.z * Kc;
    C += (size_t)blockIdx.z * pstride;
    const int lane = tid & 63;
    const int wv   = tid >> 6;
    const int quad = lane >> 4;
    const int l15  = lane & 15;
    const int wm   = (wv >> 1) * 64;    // wave m-offset in tile
    const int wn   = (wv & 1) * 32;     // wave n-offset in tile
    const int srow = tid >> 3;          // 0..31 staging row
    const int scol = (tid & 7) * 8;     // staging col (bf16 units)

    floatx4 acc[4][2];
#pragma unroll
    for (int i = 0; i < 4; ++i)
#pragma unroll
        for (int j = 0; j < 2; ++j)
            acc[i][j] = (floatx4){0.f, 0.f, 0.f, 0.f};

    const __hip_bfloat16* Aptr = A + (size_t)(bm + srow) * lda + k0 + scol;
    const __hip_bfloat16* Wptr = W + k0 + scol;

    for (int kt = 0; kt < Kc; kt += BK) {
        // stage A tile: 128 rows x 64 bf16 (4 passes of 32 rows)
#pragma unroll
        for (int p = 0; p < 4; ++p) {
            floatx4 v = *(const floatx4*)(Aptr + (size_t)(p * 32) * lda + kt);
            *(floatx4*)(&As[p * 32 + srow][scol]) = v;
        }
        // stage W tile: 64 rows x 64 bf16 (2 passes of 32 rows)
#pragma unroll
        for (int p = 0; p < 2; ++p) {
            int gw = bn + p * 32 + srow;
            floatx4 v;
            if (EPI == 0 || gw < N)
                v = *(const floatx4*)(Wptr + (size_t)gw * ldw + kt);
            else
                v = (floatx4){0.f, 0.f, 0.f, 0.f};
            *(floatx4*)(&Wsm[p * 32 + srow][scol]) = v;
        }
        __syncthreads();
#pragma unroll
        for (int ks = 0; ks < 2; ++ks) {
            short8 af[4], bw[2];
#pragma unroll
            for (int i = 0; i < 4; ++i)
                af[i] = *(const short8*)(&As[wm + i * 16 + l15][ks * 32 + quad * 8]);
#pragma unroll
            for (int j = 0; j < 2; ++j)
                bw[j] = *(const short8*)(&Wsm[wn + j * 16 + l15][ks * 32 + quad * 8]);
#pragma unroll
            for (int i = 0; i < 4; ++i)
#pragma unroll
                for (int j = 0; j < 2; ++j)
                    acc[i][j] = __builtin_amdgcn_mfma_f32_16x16x32_bf16(
                        af[i], bw[j], acc[i][j], 0, 0, 0);
        }
        __syncthreads();
    }

    // epilogue: D row = quad*4+reg, col = lane&15  (m89-verified layout)
#pragma unroll
    for (int i = 0; i < 4; ++i) {
        int m = bm + wm + i * 16 + quad * 4;
#pragma unroll
        for (int j = 0; j < 2; ++j) {
            int n = bn + wn + j * 16 + l15;
            if (EPI == 1 && n >= N) continue;
#pragma unroll
            for (int r = 0; r < 4; ++r) {
                float v = acc[i][j][r];
                if (EPI == 1) {
                    bool act = tstep < dec_len[m + r];
                    v = act ? (v + bias[n]) : 0.f;
                }
                C[(size_t)(m + r) * ldc + n] = v;
            }
        }
    }
}

// ---------------- LSTM pointwise: sum 4 split-K partials + biases, fp32 c, bf16 h ----------------
__global__ void lstm_kernel(const float* __restrict__ gpart, size_t pstride,
                            const float* __restrict__ bih, const float* __restrict__ bhh,
                            float* __restrict__ c,
                            __hip_bfloat16* __restrict__ hs1, int st1,
                            __hip_bfloat16* __restrict__ hs2, int st2,
                            const int* __restrict__ dec_len, int t) {
    int idx = blockIdx.x * 256 + threadIdx.x;   // B*DD threads
    int b = idx >> 10;
    int d = idx & 1023;
    if (t >= dec_len[b]) return;   // inactive rows keep old h,c (block-uniform branch)
    float g[4];
#pragma unroll
    for (int gate = 0; gate < 4; ++gate) {
        int o = b * 4096 + gate * 1024 + d;
        float s = bih[gate * 1024 + d] + bhh[gate * 1024 + d];
        s += gpart[o] + gpart[pstride + o] + gpart[2 * pstride + o] + gpart[3 * pstride + o];
        g[gate] = s;
    }
    float si = 1.f / (1.f + expf(-g[0]));
    float sf = 1.f / (1.f + expf(-g[1]));
    float so = 1.f / (1.f + expf(-g[3]));
    float cc = sf * c[idx] + si * tanhf(g[2]);
    float hh = so * tanhf(cc);
    c[idx] = cc;
    __hip_bfloat16 hb = __float2bfloat16(hh);
    hs1[(size_t)b * st1 + d] = hb;
    hs2[(size_t)b * st2 + d] = hb;
}

// ---------------- fused attention: scores -> softmax -> weighted sum (awe bf16 in-place) ----------------
__global__ __launch_bounds__(256) void attention_kernel(
        const float* __restrict__ att1,     // (B,NN,AA) fp32, no bias
        const float* __restrict__ att2p,    // 4 split-K partials of h1@Wd^T
        size_t pstride,
        const float* __restrict__ bf_, const float* __restrict__ bd_,
        const float* __restrict__ Wa,
        const __hip_bfloat16* __restrict__ feats_bf,   // (B,NN,FF) sorted
        __hip_bfloat16* __restrict__ x2full) {         // awe slot: row stride 4096, offset 0
    int b = blockIdx.x;
    __shared__ float av[AA];
    __shared__ float alpha[NN];
    int tid = threadIdx.x;
    int lane = tid & 63;
    int wv = tid >> 6;

    for (int a = tid; a < AA; a += 256) {
        size_t o = (size_t)b * AA + a;
        av[a] = att2p[o] + att2p[pstride + o] + att2p[2 * pstride + o] +
                att2p[3 * pstride + o] + bf_[a] + bd_[a];
    }
    __syncthreads();

    // scores (ba omitted: softmax shift-invariant)
    for (int n = wv; n < NN; n += 4) {
        const float* a1 = att1 + ((size_t)b * NN + n) * AA;
        float p = 0.f;
        for (int a = lane; a < AA; a += 64) {
            float v = a1[a] + av[a];
            p += fmaxf(v, 0.f) * Wa[a];
        }
        for (int off = 32; off; off >>= 1) p += __shfl_down(p, off);
        if (lane == 0) alpha[n] = p;
    }
    __syncthreads();

    if (wv == 0) {
        float e = (lane < NN) ? alpha[lane] : -INFINITY;
        float m = e;
        for (int off = 32; off; off >>= 1) m = fmaxf(m, __shfl_down(m, off));
        m = __shfl(m, 0);
        float ex = (lane < NN) ? expf(e - m) : 0.f;
        float s = ex;
        for (int off = 32; off; off >>= 1) s += __shfl_down(s, off);
        s = __shfl(s, 0);
        if (lane < NN) alpha[lane] = ex / s;
    }
    __syncthreads();

    const __hip_bfloat16* src = feats_bf + (size_t)b * (NN * FF);
    for (int f = tid; f < FF; f += 256) {
        float s = 0.f;
#pragma unroll
        for (int n = 0; n < NN; ++n) s += alpha[n] * __bfloat162float(src[n * FF + f]);
        x2full[(size_t)b * 4096 + f] = __float2bfloat16(s);
    }
}

// ---------------- host launcher ----------------
extern "C" void kernel_launch(void* const* d_in, const int* in_sizes, int n_in,
                              void* d_out, int out_size, void* d_ws, size_t ws_size,
                              hipStream_t stream) {
    const float* img     = (const float*)d_in[0];
    const int*   caps    = (const int*)d_in[1];
    const int*   cap_len = (const int*)d_in[2];
    const float* emb     = (const float*)d_in[3];
    const float* W1_ih   = (const float*)d_in[4];
    const float* W1_hh   = (const float*)d_in[5];
    const float* b1_ih   = (const float*)d_in[6];
    const float* b1_hh   = (const float*)d_in[7];
    const float* W2_ih   = (const float*)d_in[8];
    const float* W2_hh   = (const float*)d_in[9];
    const float* b2_ih   = (const float*)d_in[10];
    const float* b2_hh   = (const float*)d_in[11];
    const float* Wf      = (const float*)d_in[12];
    const float* bf      = (const float*)d_in[13];
    const float* Wd      = (const float*)d_in[14];
    const float* bd      = (const float*)d_in[15];
    const float* Wa      = (const float*)d_in[16];
    // d_in[17] = ba: softmax shift-invariant, unused
    const float* Wfc     = (const float*)d_in[18];
    const float* bfc     = (const float*)d_in[19];
    float* out = (float*)d_out;
    (void)in_sizes; (void)n_in; (void)out_size; (void)ws_size;

    char* ws = (char*)d_ws;
    size_t off = 0;
    auto alloc = [&](size_t bytes) -> void* {
        void* p = ws + off;
        off += (bytes + 255) & ~(size_t)255;
        return p;
    };
    int* sort_ind = (int*)alloc(B * sizeof(int));
    int* dec_len  = (int*)alloc(B * sizeof(int));
    __hip_bfloat16* W1cat    = (__hip_bfloat16*)alloc((size_t)4096 * 5120 * 2);
    __hip_bfloat16* W2cat    = (__hip_bfloat16*)alloc((size_t)4096 * 4096 * 2);
    __hip_bfloat16* Wd_bf    = (__hip_bfloat16*)alloc((size_t)AA * DD * 2);
    __hip_bfloat16* Wfc_bf   = (__hip_bfloat16*)alloc((size_t)VV * DD * 2);
    __hip_bfloat16* Wf_bf    = (__hip_bfloat16*)alloc((size_t)AA * FF * 2);
    __hip_bfloat16* feats_bf = (__hip_bfloat16*)alloc((size_t)B * NN * FF * 2);
    float* att1      = (float*)alloc((size_t)B * NN * AA * 4);
    float* g_part    = (float*)alloc((size_t)4 * B * 4096 * 4);
    float* att2_part = (float*)alloc((size_t)4 * B * AA * 4);
    __hip_bfloat16* x1full = (__hip_bfloat16*)alloc((size_t)B * 5120 * 2); // [h2|fm|emb|h1]
    __hip_bfloat16* x2full = (__hip_bfloat16*)alloc((size_t)B * 4096 * 2); // [awe|h1|h2]
    float* c1 = (float*)alloc((size_t)B * DD * 4);
    float* c2 = (float*)alloc((size_t)B * DD * 4);

    // ---- setup (runs every call: ws is re-poisoned) ----
    sort_kernel<<<1, B, 0, stream>>>(cap_len, sort_ind, dec_len);
    pack_w1_kernel<<<(4096 * 5120) / 256, 256, 0, stream>>>(W1_ih, W1_hh, W1cat);
    pack_w2_kernel<<<(4096 * 4096) / 256, 256, 0, stream>>>(W2_ih, W2_hh, W2cat);
    convert_kernel<<<(AA * DD) / 256, 256, 0, stream>>>(Wd, Wd_bf, AA * DD);
    convert_kernel<<<(VV * DD + 255) / 256, 256, 0, stream>>>(Wfc, Wfc_bf, VV * DD);
    convert_kernel<<<(AA * FF) / 256, 256, 0, stream>>>(Wf, Wf_bf, AA * FF);
    feats_bf_kernel<<<(B * NN * FF) / 256, 256, 0, stream>>>(img, sort_ind, feats_bf);
    hipMemsetAsync(x1full, 0, (size_t)B * 5120 * 2, stream);
    hipMemsetAsync(x2full, 0, (size_t)B * 4096 * 2, stream);
    hipMemsetAsync(c1, 0, (size_t)B * DD * 4, stream);
    hipMemsetAsync(c2, 0, (size_t)B * DD * 4, stream);
    fm_kernel<<<(B * FF) / 256, 256, 0, stream>>>(img, sort_ind, x1full);

    // att1 = feats_bf @ Wf^T (no bias; bf added in attention) : M=4608, N=1024, K=2048
    gemm_bf16<0><<<dim3(AA / BN, (B * NN) / BM, 1), 256, 0, stream>>>(
        feats_bf, FF, Wf_bf, FF, att1, AA, 0, AA, FF, nullptr, nullptr, 0);

    const size_t gstride = (size_t)B * 4096;
    const size_t astride = (size_t)B * AA;

    for (int t = 0; t < TT; ++t) {
        emb_gather_kernel<<<(B * EE) / 256, 256, 0, stream>>>(emb, caps, sort_ind, t, x1full);

        // g1 = [h2|fm|emb|h1] @ [W1_ih|W1_hh]^T : K=5120, split-K 4
        gemm_bf16<0><<<dim3(4096 / BN, 1, 4), 256, 0, stream>>>(
            x1full, 5120, W1cat, 5120, g_part, 4096, gstride, 4096, 1280,
            nullptr, nullptr, 0);
        lstm_kernel<<<(B * DD) / 256, 256, 0, stream>>>(
            g_part, gstride, b1_ih, b1_hh, c1,
            x1full + 4096, 5120, x2full + 2048, 4096, dec_len, t);

        // att2 = h1 @ Wd^T : K=1024, split-K 4
        gemm_bf16<0><<<dim3(AA / BN, 1, 4), 256, 0, stream>>>(
            x2full + 2048, 4096, Wd_bf, DD, att2_part, AA, astride, AA, 256,
            nullptr, nullptr, 0);

        attention_kernel<<<B, 256, 0, stream>>>(
            att1, att2_part, astride, bf, bd, Wa, feats_bf, x2full);

        // g2 = [awe|h1|h2] @ [W2_ih|W2_hh]^T : K=4096, split-K 4
        gemm_bf16<0><<<dim3(4096 / BN, 1, 4), 256, 0, stream>>>(
            x2full, 4096, W2cat, 4096, g_part, 4096, gstride, 4096, 1024,
            nullptr, nullptr, 0);
        lstm_kernel<<<(B * DD) / 256, 256, 0, stream>>>(
            g_part, gstride, b2_ih, b2_hh, c2,
            x1full + 0, 5120, x2full + 3072, 4096, dec_len, t);

        // preds[:, t, :] = active * (h2 @ Wfc^T + bfc) : N=10000, masked epilogue
        gemm_bf16<1><<<dim3((VV + BN - 1) / BN, 1, 1), 256, 0, stream>>>(
            x1full, 5120, Wfc_bf, DD, out + (size_t)t * VV, TT * VV, 0, VV, DD,
            bfc, dec_len, t);
    }
}

// Round 3
// 2046.026 us; speedup vs baseline: 7.7272x; 1.5087x over previous
//
#include <hip/hip_runtime.h>
#include <hip/hip_bf16.h>
#include <math.h>

#define B   128
#define NN  36
#define FF  2048
#define AA  1024
#define EE  1024
#define DD  1024
#define VV  10000
#define LL  20
#define TT  19

typedef __attribute__((ext_vector_type(8))) short short8;
typedef __attribute__((ext_vector_type(4))) float floatx4;

// ---------------- sort (stable descending by length) ----------------
__global__ __launch_bounds__(B) void sort_kernel(const int* __restrict__ cap_len,
                                                 int* __restrict__ sort_ind,
                                                 int* __restrict__ dec_len) {
    __shared__ int lsh[B];
    int i = threadIdx.x;
    lsh[i] = cap_len[i];
    __syncthreads();
    int li = lsh[i];
    int rank = 0;
    for (int j = 0; j < B; ++j) {
        int lj = lsh[j];
        rank += (lj > li) || (lj == li && j < i);   // stable descending
    }
    sort_ind[rank] = i;
    dec_len[rank]  = li - 1;
}

// ---------------- fp32 -> bf16 convert ----------------
__global__ void convert_kernel(const float* __restrict__ src,
                               __hip_bfloat16* __restrict__ dst, int n) {
    int i = blockIdx.x * 256 + threadIdx.x;
    if (i < n) dst[i] = __float2bfloat16(src[i]);
}

// ---------------- pack [W1_ih | W1_hh] -> bf16 (4096 x 5120) ----------------
__global__ void pack_w1_kernel(const float* __restrict__ Wih,
                               const float* __restrict__ Whh,
                               __hip_bfloat16* __restrict__ dst) {
    int i = blockIdx.x * 256 + threadIdx.x;
    int n = i / 5120, k = i % 5120;
    float v = (k < 4096) ? Wih[(size_t)n * 4096 + k] : Whh[(size_t)n * 1024 + (k - 4096)];
    dst[i] = __float2bfloat16(v);
}

// ---------------- pack [W2_ih | W2_hh] -> bf16 (4096 x 4096) ----------------
__global__ void pack_w2_kernel(const float* __restrict__ Wih,
                               const float* __restrict__ Whh,
                               __hip_bfloat16* __restrict__ dst) {
    int i = blockIdx.x * 256 + threadIdx.x;
    int n = i >> 12, k = i & 4095;
    float v = (k < 3072) ? Wih[(size_t)n * 3072 + k] : Whh[(size_t)n * 1024 + (k - 3072)];
    dst[i] = __float2bfloat16(v);
}

// ---------------- sorted feats -> bf16 ----------------
__global__ void feats_bf_kernel(const float* __restrict__ img,
                                const int* __restrict__ sort_ind,
                                __hip_bfloat16* __restrict__ dst) {
    int i = blockIdx.x * 256 + threadIdx.x;
    int b = i / (NN * FF);
    int r = i % (NN * FF);
    dst[i] = __float2bfloat16(img[(size_t)sort_ind[b] * (NN * FF) + r]);
}

// ---------------- feats_mean -> x1full slot [1024..3072) ----------------
__global__ void fm_kernel(const float* __restrict__ img,
                          const int* __restrict__ sort_ind,
                          __hip_bfloat16* __restrict__ x1full) {
    int i = blockIdx.x * 256 + threadIdx.x;
    int b = i >> 11;
    int f = i & 2047;
    const float* src = img + (size_t)sort_ind[b] * (NN * FF) + f;
    float s = 0.f;
#pragma unroll
    for (int n = 0; n < NN; ++n) s += src[n * FF];
    x1full[(size_t)b * 5120 + 1024 + f] = __float2bfloat16(s * (1.0f / NN));
}

// ---------------- emb gather (t=0 only; later steps fused into lstm2) ----------------
__global__ void emb_gather_kernel(const float* __restrict__ emb,
                                  const int* __restrict__ caps,
                                  const int* __restrict__ sort_ind,
                                  int t,
                                  __hip_bfloat16* __restrict__ x1full) {
    int i = blockIdx.x * 256 + threadIdx.x;
    int b = i >> 10;
    int e = i & 1023;
    int cap = caps[sort_ind[b] * LL + t];
    x1full[(size_t)b * 5120 + 3072 + e] = __float2bfloat16(emb[(size_t)cap * EE + e]);
}

// ---------------- bf16 MFMA GEMM ----------------
// EPI=0: fp32 partial at C + z*pstride. EPI=1: preds epilogue (bias+mask+N guard).
// EPI=2: bf16 output (att1).
#define BM 128
#define BN 64
#define BK 64
#define LDS_K 72

template<int EPI>
__global__ __launch_bounds__(256) void gemm_bf16(
        const __hip_bfloat16* __restrict__ A, int lda,
        const __hip_bfloat16* __restrict__ W, int ldw,
        float* __restrict__ C, int ldc, size_t pstride,
        int N, int Kc,
        const float* __restrict__ bias,
        const int* __restrict__ dec_len, int tstep) {
    __shared__ __align__(16) short As[BM][LDS_K];
    __shared__ __align__(16) short Wsm[BN][LDS_K];
    const int tid  = threadIdx.x;
    const int bn   = blockIdx.x * BN;
    const int bm   = blockIdx.y * BM;
    const int k0   = blockIdx.z * Kc;
    C += (size_t)blockIdx.z * pstride;
    const int lane = tid & 63;
    const int wv   = tid >> 6;
    const int quad = lane >> 4;
    const int l15  = lane & 15;
    const int wm   = (wv >> 1) * 64;
    const int wn   = (wv & 1) * 32;
    const int srow = tid >> 3;
    const int scol = (tid & 7) * 8;

    floatx4 acc[4][2];
#pragma unroll
    for (int i = 0; i < 4; ++i)
#pragma unroll
        for (int j = 0; j < 2; ++j)
            acc[i][j] = (floatx4){0.f, 0.f, 0.f, 0.f};

    const __hip_bfloat16* Aptr = A + (size_t)(bm + srow) * lda + k0 + scol;
    const __hip_bfloat16* Wptr = W + k0 + scol;

    for (int kt = 0; kt < Kc; kt += BK) {
#pragma unroll
        for (int p = 0; p < 4; ++p) {
            floatx4 v = *(const floatx4*)(Aptr + (size_t)(p * 32) * lda + kt);
            *(floatx4*)(&As[p * 32 + srow][scol]) = v;
        }
#pragma unroll
        for (int p = 0; p < 2; ++p) {
            int gw = bn + p * 32 + srow;
            floatx4 v;
            if (EPI != 1 || gw < N)
                v = *(const floatx4*)(Wptr + (size_t)gw * ldw + kt);
            else
                v = (floatx4){0.f, 0.f, 0.f, 0.f};
            *(floatx4*)(&Wsm[p * 32 + srow][scol]) = v;
        }
        __syncthreads();
#pragma unroll
        for (int ks = 0; ks < 2; ++ks) {
            short8 af[4], bw[2];
#pragma unroll
            for (int i = 0; i < 4; ++i)
                af[i] = *(const short8*)(&As[wm + i * 16 + l15][ks * 32 + quad * 8]);
#pragma unroll
            for (int j = 0; j < 2; ++j)
                bw[j] = *(const short8*)(&Wsm[wn + j * 16 + l15][ks * 32 + quad * 8]);
#pragma unroll
            for (int i = 0; i < 4; ++i)
#pragma unroll
                for (int j = 0; j < 2; ++j)
                    acc[i][j] = __builtin_amdgcn_mfma_f32_16x16x32_bf16(
                        af[i], bw[j], acc[i][j], 0, 0, 0);
        }
        __syncthreads();
    }

    // D layout: row = quad*4+reg, col = lane&15 (m89-verified)
#pragma unroll
    for (int i = 0; i < 4; ++i) {
        int m = bm + wm + i * 16 + quad * 4;
#pragma unroll
        for (int j = 0; j < 2; ++j) {
            int n = bn + wn + j * 16 + l15;
            if (EPI == 1 && n >= N) continue;
#pragma unroll
            for (int r = 0; r < 4; ++r) {
                float v = acc[i][j][r];
                if (EPI == 1) {
                    bool act = tstep < dec_len[m + r];
                    v = act ? (v + bias[n]) : 0.f;
                    C[(size_t)(m + r) * ldc + n] = v;
                } else if (EPI == 2) {
                    ((__hip_bfloat16*)C)[(size_t)(m + r) * ldc + n] = __float2bfloat16(v);
                } else {
                    C[(size_t)(m + r) * ldc + n] = v;
                }
            }
        }
    }
}

// ---------------- LSTM pointwise: sum 8 split-K partials + biases ----------------
// Optionally gathers next step's embedding into x1full emb slot (lstm2 only).
__global__ void lstm_kernel(const float* __restrict__ gpart, size_t pstride,
                            const float* __restrict__ bih, const float* __restrict__ bhh,
                            float* __restrict__ c,
                            __hip_bfloat16* __restrict__ hs1, int st1,
                            __hip_bfloat16* __restrict__ hs2, int st2,
                            const int* __restrict__ dec_len, int t,
                            const float* __restrict__ embF,
                            const int* __restrict__ caps,
                            const int* __restrict__ sort_ind,
                            __hip_bfloat16* __restrict__ embdst, int tnext) {
    int idx = blockIdx.x * 256 + threadIdx.x;   // B*DD threads
    int b = idx >> 10;
    int d = idx & 1023;
    bool act = t < dec_len[b];
    if (embdst && act) {   // rows active at t+1 are a subset of rows active at t
        int cap = caps[sort_ind[b] * LL + tnext];
        embdst[(size_t)b * 5120 + d] = __float2bfloat16(embF[(size_t)cap * EE + d]);
    }
    if (!act) return;
    float g[4];
#pragma unroll
    for (int gate = 0; gate < 4; ++gate) {
        size_t o = (size_t)b * 4096 + gate * 1024 + d;
        float s = bih[gate * 1024 + d] + bhh[gate * 1024 + d];
#pragma unroll
        for (int z = 0; z < 8; ++z) s += gpart[z * pstride + o];
        g[gate] = s;
    }
    float si = 1.f / (1.f + expf(-g[0]));
    float sf = 1.f / (1.f + expf(-g[1]));
    float so = 1.f / (1.f + expf(-g[3]));
    float cc = sf * c[idx] + si * tanhf(g[2]);
    float hh = so * tanhf(cc);
    c[idx] = cc;
    __hip_bfloat16 hb = __float2bfloat16(hh);
    hs1[(size_t)b * st1 + d] = hb;
    hs2[(size_t)b * st2 + d] = hb;
}

// ---------------- att2 partial reduce + biases: av = sum_z p[z] + bf + bd ----------------
__global__ void att2sum_kernel(const float* __restrict__ p, size_t pstride,
                               const float* __restrict__ bf_,
                               const float* __restrict__ bd_,
                               float* __restrict__ av) {
    int i = blockIdx.x * 256 + threadIdx.x;   // B*AA threads
    int a = i & 1023;
    float s = bf_[a] + bd_[a];
#pragma unroll
    for (int z = 0; z < 16; ++z) s += p[z * pstride + i];
    av[i] = s;
}

// ---------------- scores: e[b,n] = relu(att1[b,n,:] + av[b,:]) . Wa  (wave per (b,n)) ----------------
__global__ __launch_bounds__(256) void score_kernel(
        const __hip_bfloat16* __restrict__ att1,  // (B*NN, AA) bf16
        const float* __restrict__ av,             // (B, AA)
        const float* __restrict__ Wa,             // (AA)
        float* __restrict__ e) {                  // (B, NN)
    int wv = threadIdx.x >> 6;
    int lane = threadIdx.x & 63;
    int idx = blockIdx.x * 4 + wv;               // (b,n) flat, 4608 total
    int b = idx / NN;
    const __hip_bfloat16* a1 = att1 + (size_t)idx * AA + lane * 16;
    const float* avp = av + (size_t)b * AA + lane * 16;
    const float* wap = Wa + lane * 16;
    float p = 0.f;
#pragma unroll
    for (int h = 0; h < 2; ++h) {
        short8 a8 = *(const short8*)(a1 + h * 8);
        floatx4 v0 = *(const floatx4*)(avp + h * 8);
        floatx4 v1 = *(const floatx4*)(avp + h * 8 + 4);
        floatx4 w0 = *(const floatx4*)(wap + h * 8);
        floatx4 w1 = *(const floatx4*)(wap + h * 8 + 4);
        float af[8];
#pragma unroll
        for (int q = 0; q < 8; ++q) {
            union { short s; __hip_bfloat16 b; } u; u.s = a8[q];
            af[q] = __bfloat162float(u.b);
        }
#pragma unroll
        for (int q = 0; q < 4; ++q) {
            p += fmaxf(af[q] + v0[q], 0.f) * w0[q];
            p += fmaxf(af[4 + q] + v1[q], 0.f) * w1[q];
        }
    }
    for (int off = 32; off; off >>= 1) p += __shfl_down(p, off);
    if (lane == 0) e[idx] = p;
}

// ---------------- awe: softmax(e[b,:]) then weighted sum of feats -> x2full awe slot ----------------
__global__ __launch_bounds__(256) void awe_kernel(
        const float* __restrict__ e,              // (B, NN)
        const __hip_bfloat16* __restrict__ feats, // (B, NN, FF) sorted
        __hip_bfloat16* __restrict__ x2full) {    // awe slot, row stride 4096
    int b = blockIdx.x;
    int chunk = blockIdx.y;                        // 0..3, 512 f each
    __shared__ float alpha[NN];
    int tid = threadIdx.x;
    if (tid < 64) {                                // wave 0: softmax over NN=36
        float ev = (tid < NN) ? e[b * NN + tid] : -INFINITY;
        float m = ev;
        for (int off = 32; off; off >>= 1) m = fmaxf(m, __shfl_down(m, off));
        m = __shfl(m, 0);
        float ex = (tid < NN) ? expf(ev - m) : 0.f;
        float s = ex;
        for (int off = 32; off; off >>= 1) s += __shfl_down(s, off);
        s = __shfl(s, 0);
        if (tid < NN) alpha[tid] = ex / s;
    }
    __syncthreads();
    int f0 = chunk * 512 + tid * 2;
    const __hip_bfloat16* src = feats + (size_t)b * (NN * FF) + f0;
    float s0 = 0.f, s1 = 0.f;
#pragma unroll
    for (int n = 0; n < NN; ++n) {
        __hip_bfloat162 v = *(const __hip_bfloat162*)(src + n * FF);
        float af = alpha[n];
        s0 += af * __bfloat162float(v.x);
        s1 += af * __bfloat162float(v.y);
    }
    __hip_bfloat162 o;
    o.x = __float2bfloat16(s0);
    o.y = __float2bfloat16(s1);
    *(__hip_bfloat162*)(x2full + (size_t)b * 4096 + f0) = o;
}

// ---------------- host launcher ----------------
extern "C" void kernel_launch(void* const* d_in, const int* in_sizes, int n_in,
                              void* d_out, int out_size, void* d_ws, size_t ws_size,
                              hipStream_t stream) {
    const float* img     = (const float*)d_in[0];
    const int*   caps    = (const int*)d_in[1];
    const int*   cap_len = (const int*)d_in[2];
    const float* emb     = (const float*)d_in[3];
    const float* W1_ih   = (const float*)d_in[4];
    const float* W1_hh   = (const float*)d_in[5];
    const float* b1_ih   = (const float*)d_in[6];
    const float* b1_hh   = (const float*)d_in[7];
    const float* W2_ih   = (const float*)d_in[8];
    const float* W2_hh   = (const float*)d_in[9];
    const float* b2_ih   = (const float*)d_in[10];
    const float* b2_hh   = (const float*)d_in[11];
    const float* Wf      = (const float*)d_in[12];
    const float* bf      = (const float*)d_in[13];
    const float* Wd      = (const float*)d_in[14];
    const float* bd      = (const float*)d_in[15];
    const float* Wa      = (const float*)d_in[16];
    // d_in[17] = ba: softmax shift-invariant, unused
    const float* Wfc     = (const float*)d_in[18];
    const float* bfc     = (const float*)d_in[19];
    float* out = (float*)d_out;
    (void)in_sizes; (void)n_in; (void)out_size; (void)ws_size;

    char* ws = (char*)d_ws;
    size_t off = 0;
    auto alloc = [&](size_t bytes) -> void* {
        void* p = ws + off;
        off += (bytes + 255) & ~(size_t)255;
        return p;
    };
    int* sort_ind = (int*)alloc(B * sizeof(int));
    int* dec_len  = (int*)alloc(B * sizeof(int));
    __hip_bfloat16* W1cat    = (__hip_bfloat16*)alloc((size_t)4096 * 5120 * 2);
    __hip_bfloat16* W2cat    = (__hip_bfloat16*)alloc((size_t)4096 * 4096 * 2);
    __hip_bfloat16* Wd_bf    = (__hip_bfloat16*)alloc((size_t)AA * DD * 2);
    __hip_bfloat16* Wfc_bf   = (__hip_bfloat16*)alloc((size_t)VV * DD * 2);
    __hip_bfloat16* Wf_bf    = (__hip_bfloat16*)alloc((size_t)AA * FF * 2);
    __hip_bfloat16* feats_bf = (__hip_bfloat16*)alloc((size_t)B * NN * FF * 2);
    __hip_bfloat16* att1_bf  = (__hip_bfloat16*)alloc((size_t)B * NN * AA * 2);
    float* g_part    = (float*)alloc((size_t)8 * B * 4096 * 4);
    float* att2_part = (float*)alloc((size_t)16 * B * AA * 4);
    float* av        = (float*)alloc((size_t)B * AA * 4);
    float* escore    = (float*)alloc((size_t)B * NN * 4);
    __hip_bfloat16* x1full = (__hip_bfloat16*)alloc((size_t)B * 5120 * 2); // [h2|fm|emb|h1]
    __hip_bfloat16* x2full = (__hip_bfloat16*)alloc((size_t)B * 4096 * 2); // [awe|h1|h2]
    float* c1 = (float*)alloc((size_t)B * DD * 4);
    float* c2 = (float*)alloc((size_t)B * DD * 4);

    // ---- setup ----
    sort_kernel<<<1, B, 0, stream>>>(cap_len, sort_ind, dec_len);
    pack_w1_kernel<<<(4096 * 5120) / 256, 256, 0, stream>>>(W1_ih, W1_hh, W1cat);
    pack_w2_kernel<<<(4096 * 4096) / 256, 256, 0, stream>>>(W2_ih, W2_hh, W2cat);
    convert_kernel<<<(AA * DD) / 256, 256, 0, stream>>>(Wd, Wd_bf, AA * DD);
    convert_kernel<<<(VV * DD + 255) / 256, 256, 0, stream>>>(Wfc, Wfc_bf, VV * DD);
    convert_kernel<<<(AA * FF) / 256, 256, 0, stream>>>(Wf, Wf_bf, AA * FF);
    feats_bf_kernel<<<(B * NN * FF) / 256, 256, 0, stream>>>(img, sort_ind, feats_bf);
    hipMemsetAsync(x1full, 0, (size_t)B * 5120 * 2, stream);
    hipMemsetAsync(x2full, 0, (size_t)B * 4096 * 2, stream);
    hipMemsetAsync(c1, 0, (size_t)B * DD * 4, stream);
    hipMemsetAsync(c2, 0, (size_t)B * DD * 4, stream);
    fm_kernel<<<(B * FF) / 256, 256, 0, stream>>>(img, sort_ind, x1full);
    emb_gather_kernel<<<(B * EE) / 256, 256, 0, stream>>>(emb, caps, sort_ind, 0, x1full);

    // att1 = feats_bf @ Wf^T (bf16 out; bf bias folded into att2sum)
    gemm_bf16<2><<<dim3(AA / BN, (B * NN) / BM, 1), 256, 0, stream>>>(
        feats_bf, FF, Wf_bf, FF, (float*)att1_bf, AA, 0, AA, FF, nullptr, nullptr, 0);

    const size_t gstride = (size_t)B * 4096;
    const size_t astride = (size_t)B * AA;

    for (int t = 0; t < TT; ++t) {
        // g1 = [h2|fm|emb|h1] @ [W1_ih|W1_hh]^T : K=5120, split-K 8 (Kc=640)
        gemm_bf16<0><<<dim3(4096 / BN, 1, 8), 256, 0, stream>>>(
            x1full, 5120, W1cat, 5120, g_part, 4096, gstride, 4096, 640,
            nullptr, nullptr, 0);
        lstm_kernel<<<(B * DD) / 256, 256, 0, stream>>>(
            g_part, gstride, b1_ih, b1_hh, c1,
            x1full + 4096, 5120, x2full + 2048, 4096, dec_len, t,
            nullptr, nullptr, nullptr, nullptr, 0);

        // att2 partials = h1 @ Wd^T : K=1024, split-K 16 (Kc=64)
        gemm_bf16<0><<<dim3(AA / BN, 1, 16), 256, 0, stream>>>(
            x2full + 2048, 4096, Wd_bf, DD, att2_part, AA, astride, AA, 64,
            nullptr, nullptr, 0);
        att2sum_kernel<<<(B * AA) / 256, 256, 0, stream>>>(att2_part, astride, bf, bd, av);
        score_kernel<<<(B * NN) / 4, 256, 0, stream>>>(att1_bf, av, Wa, escore);
        awe_kernel<<<dim3(B, 4), 256, 0, stream>>>(escore, feats_bf, x2full);

        // g2 = [awe|h1|h2] @ [W2_ih|W2_hh]^T : K=4096, split-K 8 (Kc=512)
        gemm_bf16<0><<<dim3(4096 / BN, 1, 8), 256, 0, stream>>>(
            x2full, 4096, W2cat, 4096, g_part, 4096, gstride, 4096, 512,
            nullptr, nullptr, 0);
        lstm_kernel<<<(B * DD) / 256, 256, 0, stream>>>(
            g_part, gstride, b2_ih, b2_hh, c2,
            x1full + 0, 5120, x2full + 3072, 4096, dec_len, t,
            emb, caps, sort_ind, (t + 1 < TT) ? (x1full + 3072) : nullptr, t + 1);

        // preds[:, t, :] = active * (h2 @ Wfc^T + bfc)
        gemm_bf16<1><<<dim3((VV + BN - 1) / BN, 1, 1), 256, 0, stream>>>(
            x1full, 5120, Wfc_bf, DD, out + (size_t)t * VV, TT * VV, 0, VV, DD,
            bfc, dec_len, t);
    }
}